// Round 9
// baseline (691.398 us; speedup 1.0000x reference)
//
#include <hip/hip_runtime.h>
#include <hip/hip_fp16.h>
#include <hip/hip_cooperative_groups.h>

// NADE forward, B=512, D=1024, H=512, C=4.
// SINGLE cooperative kernel, 3 phases separated by grid.sync():
//  P0: role-split prep (V->bf16 MFMA frags | W^T*log2e, x^T | chunk partials)
//  P1: exclusive prefix over Kv=32 chunks (fp16 checkpoints A0)
//  P2: checkpointed scan: 2 waves x 256-h, bf16 MFMA logits, in-lane softmax.
// Preactivations in log2e-scaled domain: sigma = rcp(1+exp2(-a)).

namespace cg = cooperative_groups;

#define Bv 512
#define Dv 1024
#define Hv 512
#define Cv 4
#define Kv 32
#define DCv 32   // Dv / Kv

#define L2E 1.4426950408889634f
#define LN2 0.6931471805599453f

typedef __attribute__((ext_vector_type(8))) short short8;
typedef __attribute__((ext_vector_type(4))) float f32x4;
typedef __attribute__((ext_vector_type(2))) float v2f;

__device__ __forceinline__ float fexp2(float x) { return __builtin_amdgcn_exp2f(x); }
__device__ __forceinline__ float flog2(float x) { return __builtin_amdgcn_logf(x); }
__device__ __forceinline__ float frcp(float x)  { return __builtin_amdgcn_rcpf(x); }

__device__ __forceinline__ v2f fma2(v2f a, v2f b, v2f c) {
#if __has_builtin(__builtin_elementwise_fma)
    return __builtin_elementwise_fma(a, b, c);
#else
    v2f r; r.x = fmaf(a.x, b.x, c.x); r.y = fmaf(a.y, b.y, c.y); return r;
#endif
}

// pack two f32 -> bf16x2 by truncation (1 v_perm_b32); lo in low half
__device__ __forceinline__ unsigned bf16pk(float lo, float hi) {
    return __builtin_amdgcn_perm(__float_as_uint(hi), __float_as_uint(lo), 0x07060302u);
}
__device__ __forceinline__ unsigned short bf16rne(float f) {
    unsigned u = __float_as_uint(f);
    return (unsigned short)((u + 0x7FFFu + ((u >> 16) & 1u)) >> 16);
}

__global__ __launch_bounds__(128, 4) void k_all(
        const float* __restrict__ x, const float* __restrict__ V,
        const float* __restrict__ bbias, const float* __restrict__ W,
        const float* __restrict__ cb,
        unsigned short* __restrict__ VtA4, float* __restrict__ WtL,
        float* __restrict__ xt, __half* __restrict__ A0,
        float* __restrict__ out) {
    __shared__ __align__(16) char smem[16384];
    const int bid = blockIdx.x;
    const int tid = threadIdx.x;
    cg::grid_group grid = cg::this_grid();

    // ================= PHASE 0: prep =================
    if (bid < 256) {
        // V -> VtA4 MFMA A-fragments (bf16 RNE), d-tile of 4.
        // VtA4[((d*16+hb)*16 + q*4 + c)*8 + j], elem = V[h=hb*32+q*8+j][d][c]
        unsigned short* tile = (unsigned short*)smem;   // 16 KiB
        const int d0 = bid * 4;
#pragma unroll
        for (int p = 0; p < 16; ++p) {
            int idx = p * 128 + tid;        // 0..2047
            int dd = idx & 3;
            int h  = idx >> 2;              // 0..511
            float4 v = *(const float4*)(V + ((size_t)h * Dv + d0 + dd) * Cv);
            int hb = h >> 5, q = (h >> 3) & 3, j = h & 7;
            int base = ((dd * 16 + hb) * 16 + q * 4) * 8 + j;
            tile[base + 0]  = bf16rne(v.x);
            tile[base + 8]  = bf16rne(v.y);
            tile[base + 16] = bf16rne(v.z);
            tile[base + 24] = bf16rne(v.w);
        }
        __syncthreads();
        uint4* dst = (uint4*)(VtA4 + (size_t)d0 * 2048);
        const uint4* src = (const uint4*)tile;
#pragma unroll
        for (int p = 0; p < 8; ++p)
            dst[p * 128 + tid] = src[p * 128 + tid];
    } else if (bid < 768) {
        // transposes in 64x32 tiles: W -> WtL (*L2E), x -> xt
        float (*td)[33] = (float (*)[33])smem;          // 64 x 33 floats
        const int idx0 = bid - 256;
        const int mb   = idx0 >> 8;                     // 0: W, 1: x
        const int tile = idx0 & 255;
        const int tr   = tile >> 5;                     // 0..7  (64-row tile)
        const int tc   = tile & 31;                     // 0..31 (32-col tile)
        const float* src = mb ? x : W;
        float* dst       = mb ? xt : WtL;
        const float scale = mb ? 1.0f : L2E;
#pragma unroll
        for (int p = 0; p < 4; ++p) {
            int idx = p * 128 + tid;       // 0..511
            int c4  = idx & 7;
            int row = idx >> 3;            // 0..63
            float4 v = *(const float4*)(src + (size_t)(tr * 64 + row) * Dv + tc * 32 + c4 * 4);
            td[row][c4 * 4 + 0] = v.x;
            td[row][c4 * 4 + 1] = v.y;
            td[row][c4 * 4 + 2] = v.z;
            td[row][c4 * 4 + 3] = v.w;
        }
        __syncthreads();
#pragma unroll
        for (int p = 0; p < 4; ++p) {
            int idx  = p * 128 + tid;      // 0..511
            int dc4  = idx & 15;
            int drow = idx >> 4;           // 0..31
            float4 o = make_float4(td[dc4 * 4 + 0][drow] * scale,
                                   td[dc4 * 4 + 1][drow] * scale,
                                   td[dc4 * 4 + 2][drow] * scale,
                                   td[dc4 * 4 + 3][drow] * scale);
            *(float4*)(dst + (size_t)(tc * 32 + drow) * Hv + tr * 64 + dc4 * 4) = o;
        }
    } else {
        // chunk partials: A0[k][b][h] = L2E * sum_{d in chunk} x[b,d]*W[h,d]
        float* xs = (float*)smem;          // xs[j][68] floats, j=0..15
        const int pbi = bid - 768;         // 0..255
        const int k   = pbi >> 3;          // 0..31
        const int bg0 = (pbi & 7) * 64;    // 64 batches per block
        const int d0  = k * DCv;           // note: partial covers first 16 d? NO:
        // chunk is DCv=32 d wide -> stage 32 d.
        // xs[j][68], j = 0..31: 32*68*4 = 8704 B
#pragma unroll
        for (int p = 0; p < 4; ++p) {
            int idx = p * 128 + tid;       // 0..511 -> 64 b x 8 f4 (32 d)
            int q4 = idx & 7;
            int g  = idx >> 3;             // 0..63
            float4 v = *(const float4*)(x + (size_t)(bg0 + g) * Dv + d0 + q4 * 4);
            xs[(q4 * 4 + 0) * 68 + g] = v.x;
            xs[(q4 * 4 + 1) * 68 + g] = v.y;
            xs[(q4 * 4 + 2) * 68 + g] = v.z;
            xs[(q4 * 4 + 3) * 68 + g] = v.w;
        }
        __syncthreads();
#pragma unroll
        for (int hx = 0; hx < 4; ++hx) {
            const int h = tid + hx * 128;
            float wr[DCv];
            const float* wp = W + (size_t)h * Dv + d0;
#pragma unroll
            for (int j4 = 0; j4 < DCv; j4 += 4)
                *(float4*)(wr + j4) = *(const float4*)(wp + j4);
#pragma unroll
            for (int u = 0; u < 8; ++u) {
                float acc[8];
#pragma unroll
                for (int g = 0; g < 8; ++g) acc[g] = 0.0f;
#pragma unroll
                for (int j = 0; j < DCv; ++j) {
                    float wv = wr[j];
                    const float4 xa = *(const float4*)(xs + j * 68 + u * 8);
                    const float4 xb = *(const float4*)(xs + j * 68 + u * 8 + 4);
                    acc[0] = fmaf(xa.x, wv, acc[0]);
                    acc[1] = fmaf(xa.y, wv, acc[1]);
                    acc[2] = fmaf(xa.z, wv, acc[2]);
                    acc[3] = fmaf(xa.w, wv, acc[3]);
                    acc[4] = fmaf(xb.x, wv, acc[4]);
                    acc[5] = fmaf(xb.y, wv, acc[5]);
                    acc[6] = fmaf(xb.z, wv, acc[6]);
                    acc[7] = fmaf(xb.w, wv, acc[7]);
                }
#pragma unroll
                for (int g = 0; g < 8; ++g)
                    A0[((size_t)k * Bv + bg0 + u * 8 + g) * Hv + h] =
                        __float2half(acc[g] * L2E);
            }
        }
    }

    grid.sync();

    // ================= PHASE 1: exclusive prefix over chunks =================
    {
#pragma unroll
        for (int it = 0; it < 2; ++it) {
            int gid = it * 131072 + bid * 128 + tid;   // 0..262143
            int h = gid & (Hv - 1);
            int b = gid >> 9;
            float run = cb[h] * L2E;
            __half* p = A0 + (size_t)b * Hv + h;
#pragma unroll 4
            for (int k = 0; k < Kv; ++k) {
                float t = __half2float(p[(size_t)k * Bv * Hv]);
                p[(size_t)k * Bv * Hv] = __float2half(run);
                run += t;
            }
        }
    }

    grid.sync();

    // ================= PHASE 2: main scan =================
    {
        f32x4 (*red)[2][2][64] = (f32x4 (*)[2][2][64])smem;  // [dbuf][step][hhalf][lane]
        const int k    = bid >> 5;
        const int bg   = bid & 31;
        const int wv   = tid >> 6;
        const int lane = tid & 63;
        const int bl   = lane & 15;
        const int quad = lane >> 4;
        const int b    = bg * 16 + bl;
        const int d0   = k * DCv;

        v2f a2[32];
        {
            const __half* ap = A0 + ((size_t)k * Bv + b) * Hv + wv * 256 + quad * 8;
#pragma unroll
            for (int kb = 0; kb < 8; ++kb) {
                union { uint4 u; __half2 h2[4]; } t;
                t.u = *(const uint4*)(ap + kb * 32);
#pragma unroll
                for (int tt = 0; tt < 4; ++tt) {
                    float2 f = __half22float2(t.h2[tt]);
                    a2[kb * 4 + tt] = (v2f){f.x, f.y};
                }
            }
        }

        const int blc = (bl < 4) ? bl : 0;
        const unsigned short* vp = VtA4 + (((size_t)d0 * 16 + wv * 8) * 16 + quad * 4 + blc) * 8;
        const float* wp = WtL + (size_t)d0 * Hv + wv * 256 + quad * 8;
        const float* xp = xt + (size_t)d0 * Bv + b;
        const float* bp = bbias + (d0 + wv) * Cv;
        float* sy = out + (size_t)b * Dv * Cv + (d0 + wv) * Cv;
        float* spp = sy + (size_t)Bv * Dv * Cv;

        for (int i1 = 0; i1 < DCv / 2; ++i1) {
            float xdA = xp[0];
            float xdB = xp[Bv];
            float4 bbv = *(const float4*)bp;

            // step A
            f32x4 acc0 = {0.f, 0.f, 0.f, 0.f};
            f32x4 acc1 = {0.f, 0.f, 0.f, 0.f};
#pragma unroll
            for (int kb = 0; kb < 8; ++kb) {
                union { unsigned u[4]; short8 s; } cv;
#pragma unroll
                for (int t = 0; t < 4; ++t) {
                    v2f aa = a2[kb * 4 + t];
                    float s0 = frcp(1.0f + fexp2(-aa.x));
                    float s1 = frcp(1.0f + fexp2(-aa.y));
                    cv.u[t] = bf16pk(s0, s1);
                }
                short8 af = *(const short8*)(vp + kb * 128);
                if (kb & 1)
                    acc1 = __builtin_amdgcn_mfma_f32_16x16x32_bf16(af, cv.s, acc1, 0, 0, 0);
                else
                    acc0 = __builtin_amdgcn_mfma_f32_16x16x32_bf16(af, cv.s, acc0, 0, 0, 0);
            }
            f32x4 accA = acc0 + acc1;
            v2f xA2 = {xdA, xdA};
#pragma unroll
            for (int kb = 0; kb < 8; ++kb) {
                float4 w0 = *(const float4*)(wp + kb * 32);
                float4 w1 = *(const float4*)(wp + kb * 32 + 4);
                a2[kb*4+0] = fma2(xA2, (v2f){w0.x, w0.y}, a2[kb*4+0]);
                a2[kb*4+1] = fma2(xA2, (v2f){w0.z, w0.w}, a2[kb*4+1]);
                a2[kb*4+2] = fma2(xA2, (v2f){w1.x, w1.y}, a2[kb*4+2]);
                a2[kb*4+3] = fma2(xA2, (v2f){w1.z, w1.w}, a2[kb*4+3]);
            }

            // step B
            f32x4 acc2 = {0.f, 0.f, 0.f, 0.f};
            f32x4 acc3 = {0.f, 0.f, 0.f, 0.f};
#pragma unroll
            for (int kb = 0; kb < 8; ++kb) {
                union { unsigned u[4]; short8 s; } cv;
#pragma unroll
                for (int t = 0; t < 4; ++t) {
                    v2f aa = a2[kb * 4 + t];
                    float s0 = frcp(1.0f + fexp2(-aa.x));
                    float s1 = frcp(1.0f + fexp2(-aa.y));
                    cv.u[t] = bf16pk(s0, s1);
                }
                short8 af = *(const short8*)(vp + 2048 + kb * 128);
                if (kb & 1)
                    acc3 = __builtin_amdgcn_mfma_f32_16x16x32_bf16(af, cv.s, acc3, 0, 0, 0);
                else
                    acc2 = __builtin_amdgcn_mfma_f32_16x16x32_bf16(af, cv.s, acc2, 0, 0, 0);
            }
            f32x4 accB = acc2 + acc3;
            v2f xB2 = {xdB, xdB};
#pragma unroll
            for (int kb = 0; kb < 8; ++kb) {
                float4 w0 = *(const float4*)(wp + Hv + kb * 32);
                float4 w1 = *(const float4*)(wp + Hv + kb * 32 + 4);
                a2[kb*4+0] = fma2(xB2, (v2f){w0.x, w0.y}, a2[kb*4+0]);
                a2[kb*4+1] = fma2(xB2, (v2f){w0.z, w0.w}, a2[kb*4+1]);
                a2[kb*4+2] = fma2(xB2, (v2f){w1.x, w1.y}, a2[kb*4+2]);
                a2[kb*4+3] = fma2(xB2, (v2f){w1.z, w1.w}, a2[kb*4+3]);
            }

            red[i1 & 1][0][wv][lane] = accA;
            red[i1 & 1][1][wv][lane] = accB;
            __syncthreads();

            f32x4 s = red[i1 & 1][wv][0][lane] + red[i1 & 1][wv][1][lane];
            float w0 = s.x + bbv.x;
            float w1 = s.y + bbv.y;
            float w2 = s.z + bbv.z;
            float w3 = s.w + bbv.w;
            float mx = fmaxf(fmaxf(w0, w1), fmaxf(w2, w3));
            float e0 = fexp2((w0 - mx) * L2E);
            float e1 = fexp2((w1 - mx) * L2E);
            float e2 = fexp2((w2 - mx) * L2E);
            float e3 = fexp2((w3 - mx) * L2E);
            float lse = mx + flog2(e0 + e1 + e2 + e3) * LN2;
            if (quad == 0) {
                *(float4*)sy  = make_float4(w0, w1, w2, w3);
                *(float4*)spp = make_float4(w0 - lse, w1 - lse, w2 - lse, w3 - lse);
            }

            vp += 2 * 2048;
            wp += 2 * Hv;
            xp += 2 * Bv;
            bp += 2 * Cv;
            sy += 2 * Cv;
            spp += 2 * Cv;
        }
    }
}

extern "C" void kernel_launch(void* const* d_in, const int* in_sizes, int n_in,
                              void* d_out, int out_size, void* d_ws, size_t ws_size,
                              hipStream_t stream) {
    const float* x  = (const float*)d_in[0];   // [B, D]
    const float* V  = (const float*)d_in[1];   // [H, D, C]
    const float* bb = (const float*)d_in[2];   // [D, C]
    const float* W  = (const float*)d_in[3];   // [H, D]
    const float* cb = (const float*)d_in[4];   // [1, H]
    float* out = (float*)d_out;                // y_hat [B*D*C] then p_hat

    char* ws = (char*)d_ws;
    unsigned short* VtA4 = (unsigned short*)ws;                 // 4 MiB
    float* WtL = (float*)(ws + (size_t)4 * 1024 * 1024);        // 2 MiB
    float* xt  = (float*)(ws + (size_t)6 * 1024 * 1024);        // 2 MiB
    __half* A0 = (__half*)(ws + (size_t)8 * 1024 * 1024);       // 16 MiB (Kv*B*H half)

    void* args[] = {(void*)&x, (void*)&V, (void*)&bb, (void*)&W, (void*)&cb,
                    (void*)&VtA4, (void*)&WtL, (void*)&xt, (void*)&A0, (void*)&out};
    hipLaunchCooperativeKernel((const void*)k_all, dim3(Kv * 32), dim3(128),
                               args, 0, stream);
}